// Round 18
// baseline (501.449 us; speedup 1.0000x reference)
//
#include <hip/hip_runtime.h>
#include <hip/hip_bf16.h>
#include <hip/hip_fp8.h>
#include <cstdint>
#include <cstddef>

// Problem constants
#define NN     20000     // nodes
#define NF     128       // in features
#define NH     56        // heads
#define OC     32        // out channels per head
#define DD1    1792      // NH*OC
#define NE     100000    // edges (before self loops)
#define ETOT   120000    // edges + self loops
#define NG     50        // graphs
#define EPS_BN 1e-5f
#define GRP    16        // nodes per wave in aggregate
#define EB     16        // edge batch (round-5 proven single-buffer)
#define W1SCL  8.0f      // W1 pre-scale into fp8 range (std 0.088 -> 0.71)
#define W2SCL  16.0f     // W2 pre-scale into fp8 range

typedef __bf16 bf16x8 __attribute__((ext_vector_type(8)));
typedef float  floatx4 __attribute__((ext_vector_type(4)));
typedef float  floatx2 __attribute__((ext_vector_type(2)));
typedef long   longx2  __attribute__((ext_vector_type(2)));
typedef unsigned int u32;
typedef __attribute__((address_space(1))) u32 gu32;
typedef __attribute__((address_space(3))) u32 lu32;

__device__ __forceinline__ void async_copy16(void* lds, const void* g) {
    __builtin_amdgcn_global_load_lds((gu32*)const_cast<void*>(g), (lu32*)lds, 16, 0, 0);
}

// 16B LDS load via the bf16x8-typed pattern (emits ds_read_b128), bit-cast to the
// fp8-MFMA operand pair.
__device__ __forceinline__ longx2 ld_lds16(const unsigned char* p) {
    bf16x8 raw = *(const bf16x8*)p;
    return __builtin_bit_cast(longx2, raw);
}

// decode 4 fp8 (e4m3, packed in u32) to 4 floats (HW cvt when available)
__device__ __forceinline__ void dec_fp8x4(u32 u, float* v) {
#if __has_builtin(__builtin_amdgcn_cvt_pk_f32_fp8)
    floatx2 lo = __builtin_amdgcn_cvt_pk_f32_fp8(u, false);
    floatx2 hi = __builtin_amdgcn_cvt_pk_f32_fp8(u, true);
    v[0] = lo[0]; v[1] = lo[1]; v[2] = hi[0]; v[3] = hi[1];
#else
    #pragma unroll
    for (int b = 0; b < 4; ++b) {
        __hip_fp8_e4m3 t;
        t.__x = (u >> (8 * b)) & 0xff;
        v[b] = (float)t;
    }
#endif
}

__device__ __forceinline__ u32 enc_fp8x4(float v0, float v1, float v2, float v3) {
#if __has_builtin(__builtin_amdgcn_cvt_pk_fp8_f32)
    u32 p01 = (u32)__builtin_amdgcn_cvt_pk_fp8_f32(v0, v1, 0, false);
    u32 p23 = (u32)__builtin_amdgcn_cvt_pk_fp8_f32(v2, v3, 0, false);
    return (p01 & 0xffff) | (p23 << 16);
#else
    __hip_fp8_e4m3 t0(v0), t1(v1), t2(v2), t3(v3);
    return (u32)t0.__x | ((u32)t1.__x << 8) | ((u32)t2.__x << 16) | ((u32)t3.__x << 24);
#endif
}

__device__ __forceinline__ void fma_fp8x4(u32 u, float a, float* acc) {
    float v[4];
    dec_fp8x4(u, v);
    #pragma unroll
    for (int b = 0; b < 4; ++b) acc[b] += a * v[b];
}

// ---- 16-lane row sum via DPP (VALU pipe, NO LDS traffic; round-13 proven) ----
template <int CTRL>
__device__ __forceinline__ float dpp_row_add(float x) {
    int v = __builtin_amdgcn_mov_dpp(__float_as_int(x), CTRL, 0xf, 0xf, true);
    return x + __int_as_float(v);
}
__device__ __forceinline__ float dpp_add16(float x) {
    x = dpp_row_add<0x128>(x);   // row_ror:8
    x = dpp_row_add<0x124>(x);   // row_ror:4
    x = dpp_row_add<78>(x);      // quad_perm [2,3,0,1] = xor2
    x = dpp_row_add<177>(x);     // quad_perm [1,0,3,2] = xor1
    return x;
}

// ---------------- elementwise cast fp32 -> fp8 (x is N(0,1): native e4m3 range) ----------------
__global__ __launch_bounds__(256) void cast_fp8_kernel(const float* __restrict__ in,
                                                       unsigned char* __restrict__ out, int n) {
    int i = blockIdx.x * 256 + threadIdx.x;
    if (i < n) {
        __hip_fp8_e4m3 t(in[i]);
        out[i] = t.__x;
    }
}

// ---------------- tiled transpose + fp8 cast with pre-scale ----------------
__global__ __launch_bounds__(256) void transpose_fp8_kernel(const float* __restrict__ in,
                                                            unsigned char* __restrict__ out,
                                                            int R, int C, float scale) {
    __shared__ float tile[32][33];
    int c0 = blockIdx.x * 32, r0 = blockIdx.y * 32;
    int tx = threadIdx.x & 31, ty = threadIdx.x >> 5;
    #pragma unroll
    for (int i = 0; i < 32; i += 8) {
        int r = r0 + ty + i, c = c0 + tx;
        if (r < R && c < C) tile[ty + i][tx] = in[(size_t)r * C + c];
    }
    __syncthreads();
    #pragma unroll
    for (int i = 0; i < 32; i += 8) {
        int c = c0 + ty + i, r = r0 + tx;
        if (c < C && r < R) {
            __hip_fp8_e4m3 t(tile[tx][ty + i] * scale);
            out[(size_t)c * R + r] = t.__x;
        }
    }
}

// ---------------- CSR build: histogram / scan / scatter ----------------
__global__ __launch_bounds__(256) void hist_kernel(const int* __restrict__ ei, int* __restrict__ deg) {
    int i = blockIdx.x * 256 + threadIdx.x;
    if (i >= ETOT) return;
    int dst = (i < NE) ? ei[NE + i] : (i - NE);
    atomicAdd(&deg[dst], 1);
}

__global__ __launch_bounds__(1024) void scan_kernel(const int* __restrict__ deg,
                                                    int* __restrict__ rowptr,
                                                    int* __restrict__ cursor) {
    __shared__ int buf[1024];
    int t = threadIdx.x;
    const int CH = (NN + 1023) >> 10;   // 20
    int base = t * CH;
    int s = 0;
    for (int j = 0; j < CH; ++j) { int idx = base + j; if (idx < NN) s += deg[idx]; }
    buf[t] = s;
    __syncthreads();
    for (int off = 1; off < 1024; off <<= 1) {
        int v = (t >= off) ? buf[t - off] : 0;
        __syncthreads();
        buf[t] += v;
        __syncthreads();
    }
    int run = buf[t] - s;   // exclusive
    for (int j = 0; j < CH; ++j) {
        int idx = base + j;
        if (idx < NN) { rowptr[idx] = run; cursor[idx] = run; run += deg[idx]; }
    }
    if (t == 1023) rowptr[NN] = buf[1023];
}

__global__ __launch_bounds__(256) void scatter_kernel(const int* __restrict__ ei,
                                                      int* __restrict__ cursor,
                                                      int* __restrict__ csr_src) {
    int i = blockIdx.x * 256 + threadIdx.x;
    if (i >= ETOT) return;
    int s, d;
    if (i < NE) { s = ei[i]; d = ei[NE + i]; } else { s = i - NE; d = i - NE; }
    int pos = atomicAdd(&cursor[d], 1);
    csr_src[pos] = s;
}

// ---------------- fp8 MFMA GEMM (BOTH layers), 192x256, BK=128, 3-phase ----------------
// k-permutation: sub-slice (j,half), lane qq supplies k from chunk j*4+qq (positional
// k-matching, A/B share the formula); chunk index (j*4+qq)^(row&7) is bank-exact with
// the long-proven bf16 pattern (round 17: SQ_LDS_BANK_CONFLICT == 0).
// NT==1 (layer 1, K=128): stage kt is clamped to NT-1; the redundant restage writes
// byte-identical data, so the stage-into-read-buffer overlap is vacuously safe and
// vmcnt accounting is unchanged. inv_scale un-scales the pre-scaled fp8 B operand
// (folded into epilogue quantize and the fused score weights).
__global__ __launch_bounds__(512, 2) void gemm_fp8(const unsigned char* __restrict__ A,
                                                   const unsigned char* __restrict__ Bt,
                                                   unsigned char* __restrict__ C8,
                                                   const float* __restrict__ att_src,
                                                   const float* __restrict__ att_dst,
                                                   float* __restrict__ as_,
                                                   float* __restrict__ ad_,
                                                   int M, int N, int K, float inv_scale) {
    __shared__ __align__(16) unsigned char lds8[2][57344];  // per buf: A[192][128B] | B[256][128B]
    const int tid  = threadIdx.x;
    const int lane = tid & 63, wave = tid >> 6;
    const int wm = wave >> 2, wn = wave & 3;     // 2 x 4 wave grid; per-wave C: 96 x 64

    const int nbx = N >> 8;                      // 7
    const int nby = (M + 191) / 192;             // 105
    const int nwg = nbx * nby;                   // 735
    const int q = nwg >> 3, r = nwg & 7;
    const int xcd = blockIdx.x & 7, bidx = blockIdx.x >> 3;
    const int wg = (xcd < r ? xcd * (q + 1) : r * (q + 1) + (xcd - r) * q) + bidx;
    const int by = wg / nbx, bx = wg - by * nbx;
    const int m0 = by * 192, n0 = bx << 8;

    const int NT = K >> 7;                       // K-tiles of 128: 14 (L2) / 1 (L1)

    const int qq = lane >> 4, rr = lane & 15;

    auto stageA = [&](int kt, int b) {           // 192 rows x 8 chunks = 1536 slots = 3/thread
        if (kt > NT - 1) kt = NT - 1;            // NT==1 clamp: restage identical data (benign)
        #pragma unroll
        for (int i = 0; i < 3; ++i) {
            int slot = i * 512 + tid;
            int row = slot >> 3, pch = slot & 7;
            int lc = pch ^ (row & 7);            // pre-swizzled global source (rule #21)
            int gr = m0 + row; if (gr > M - 1) gr = M - 1;
            async_copy16(&lds8[b][slot * 16], A + (size_t)gr * K + (kt << 7) + lc * 16);
        }
    };
    auto stageB = [&](int kt, int b) {           // 256 rows x 8 chunks = 2048 slots = 4/thread
        if (kt > NT - 1) kt = NT - 1;
        #pragma unroll
        for (int i = 0; i < 4; ++i) {
            int slot = i * 512 + tid;
            int row = slot >> 3, pch = slot & 7;
            int lc = pch ^ (row & 7);
            async_copy16(&lds8[b][24576 + slot * 16], Bt + (size_t)(n0 + row) * K + (kt << 7) + lc * 16);
        }
    };

    floatx4 zero = {0.f, 0.f, 0.f, 0.f};
    floatx4 acc[6][4];
    #pragma unroll
    for (int i = 0; i < 6; ++i)
        #pragma unroll
        for (int jj = 0; jj < 4; ++jj) acc[i][jj] = zero;

    longx2 aF[3][2], bA[2][2], bB[2][2];         // [frag][j]: .x = half 0, .y = half 1

    auto loadA = [&](int b, int mg) {
        #pragma unroll
        for (int mf = 0; mf < 3; ++mf)
            #pragma unroll
            for (int j = 0; j < 2; ++j) {
                int row = wm * 96 + mg * 48 + mf * 16 + rr;
                int ch = ((j << 2) + qq) ^ (row & 7);        // bank-exact with bf16 pattern
                aF[mf][j] = ld_lds16(&lds8[b][row * 128 + ch * 16]);
            }
    };
    auto loadB = [&](int b, longx2 (&bF)[2][2], int ng) {
        #pragma unroll
        for (int nf = 0; nf < 2; ++nf)
            #pragma unroll
            for (int j = 0; j < 2; ++j) {
                int row = wn * 64 + (ng * 2 + nf) * 16 + rr;
                int ch = ((j << 2) + qq) ^ (row & 7);
                bF[nf][j] = ld_lds16(&lds8[b][24576 + row * 128 + ch * 16]);
            }
    };
    auto mfmaQ = [&](int mg, int ng, longx2 (&bF)[2][2]) {   // 24 MFMA quadrant (K=128)
        #pragma unroll
        for (int mf = 0; mf < 3; ++mf)
            #pragma unroll
            for (int nf = 0; nf < 2; ++nf)
                #pragma unroll
                for (int j = 0; j < 2; ++j)
                    #pragma unroll
                    for (int h = 0; h < 2; ++h)
                        acc[mg * 3 + mf][ng * 2 + nf] = __builtin_amdgcn_mfma_f32_16x16x32_fp8_fp8(
                            aF[mf][j][h], bF[nf][j][h], acc[mg * 3 + mf][ng * 2 + nf], 0, 0, 0);
    };

#define SB0 __builtin_amdgcn_sched_barrier(0)
#define GBAR do { SB0; __builtin_amdgcn_s_barrier(); SB0; } while (0)

    stageB(0, 0); stageA(0, 0);
    stageB(1, 1); stageA(1, 1);
    SB0;
    asm volatile("s_waitcnt vmcnt(7)" ::: "memory");
    GBAR;

    for (int t = 0; t < NT; ++t) {
        const int p = t & 1;
        int tp = t + 2; while (tp >= NT) tp -= 2;            // parity-preserving tail clamp
        if (tp < 0) tp = 0;

        loadA(p, 0); loadB(p, bA, 0);
        GBAR;
        __builtin_amdgcn_s_setprio(1);
        mfmaQ(0, 0, bA);
        __builtin_amdgcn_s_setprio(0);
        GBAR;

        loadB(p, bB, 1);
        stageB(tp, p);
        GBAR;
        __builtin_amdgcn_s_setprio(1);
        mfmaQ(0, 1, bB);
        __builtin_amdgcn_s_setprio(0);
        GBAR;

        loadA(p, 1);
        stageA(tp, p);
        SB0;
        asm volatile("s_waitcnt vmcnt(7)" ::: "memory");
        GBAR;
        __builtin_amdgcn_s_setprio(1);
        mfmaQ(1, 1, bB);
        mfmaQ(1, 0, bA);
        __builtin_amdgcn_s_setprio(0);
        GBAR;
    }
#undef GBAR
#undef SB0

    const float scl = inv_scale;

    // epilogue 1: unscale + fp8 quantize + store
    #pragma unroll
    for (int mt = 0; mt < 6; ++mt) {
        #pragma unroll
        for (int r4 = 0; r4 < 4; ++r4) {
            int rowc = m0 + wm * 96 + mt * 16 + (lane >> 4) * 4 + r4;
            if (rowc < M) {
                u32 word = enc_fp8x4(acc[mt][0][r4] * scl, acc[mt][1][r4] * scl,
                                     acc[mt][2][r4] * scl, acc[mt][3][r4] * scl);
                unsigned char q8[4] = { (unsigned char)(word & 0xff), (unsigned char)((word >> 8) & 0xff),
                                        (unsigned char)((word >> 16) & 0xff), (unsigned char)(word >> 24) };
                #pragma unroll
                for (int nt = 0; nt < 4; ++nt) {
                    int col = n0 + wn * 64 + nt * 16 + (lane & 15);
                    C8[(size_t)rowc * N + col] = q8[nt];
                }
            }
        }
    }

    // epilogue 2: fused attention scores (scale folded into the att weights; DPP row-sum)
    {
        const int li = lane & 15;
        const int h0 = bx * 8 + wn * 2;
        float ws00 = att_src[(h0)     * OC + li] * scl,  ws01 = att_src[(h0)     * OC + 16 + li] * scl;
        float ws10 = att_src[(h0 + 1) * OC + li] * scl,  ws11 = att_src[(h0 + 1) * OC + 16 + li] * scl;
        float wd00 = att_dst[(h0)     * OC + li] * scl,  wd01 = att_dst[(h0)     * OC + 16 + li] * scl;
        float wd10 = att_dst[(h0 + 1) * OC + li] * scl,  wd11 = att_dst[(h0 + 1) * OC + 16 + li] * scl;
        #pragma unroll
        for (int mt = 0; mt < 6; ++mt) {
            #pragma unroll
            for (int r4 = 0; r4 < 4; ++r4) {
                float s0 = dpp_add16(acc[mt][0][r4] * ws00 + acc[mt][1][r4] * ws01);
                float s1 = dpp_add16(acc[mt][2][r4] * ws10 + acc[mt][3][r4] * ws11);
                float d0 = dpp_add16(acc[mt][0][r4] * wd00 + acc[mt][1][r4] * wd01);
                float d1 = dpp_add16(acc[mt][2][r4] * wd10 + acc[mt][3][r4] * wd11);
                int rowc = m0 + wm * 96 + mt * 16 + (lane >> 4) * 4 + r4;
                if (li == 0 && rowc < M) {
                    as_[(size_t)rowc * NH + h0]     = s0;
                    as_[(size_t)rowc * NH + h0 + 1] = s1;
                    ad_[(size_t)rowc * NH + h0]     = d0;
                    ad_[(size_t)rowc * NH + h0 + 1] = d1;
                }
            }
        }
    }
}

// ---------------- node-boundary flush for the fused streaming aggregate ----------------
// LAYER==1: FP8 h1p[cur][slice] = fp8(BN1(ELU(acc/den + b1)))  (feeds gemm_fp8's A)
// LAYER==2: head-reduce in-wave, write per-slice partial to h2part[cur][f][32]
template <int LAYER>
__device__ __forceinline__ void flush_node(float* acc, float den, int cur, int f, int lane,
                                           const float* __restrict__ bias,
                                           const float* __restrict__ bng,
                                           const float* __restrict__ bnb,
                                           const float* __restrict__ bnm,
                                           const float* __restrict__ bnv,
                                           void* __restrict__ outp) {
    float inv = 1.f / den;
    #pragma unroll
    for (int k = 0; k < 4; ++k) acc[k] *= inv;

    if constexpr (LAYER == 1) {
        int d0 = f * 256 + lane * 4;
        float v0 = acc[0] + bias[d0 + 0];
        float v1 = acc[1] + bias[d0 + 1];
        float v2 = acc[2] + bias[d0 + 2];
        float v3 = acc[3] + bias[d0 + 3];
        v0 = v0 > 0.f ? v0 : expm1f(v0);
        v1 = v1 > 0.f ? v1 : expm1f(v1);
        v2 = v2 > 0.f ? v2 : expm1f(v2);
        v3 = v3 > 0.f ? v3 : expm1f(v3);
        v0 = (v0 - bnm[d0 + 0]) * rsqrtf(bnv[d0 + 0] + EPS_BN) * bng[d0 + 0] + bnb[d0 + 0];
        v1 = (v1 - bnm[d0 + 1]) * rsqrtf(bnv[d0 + 1] + EPS_BN) * bng[d0 + 1] + bnb[d0 + 1];
        v2 = (v2 - bnm[d0 + 2]) * rsqrtf(bnv[d0 + 2] + EPS_BN) * bng[d0 + 2] + bnb[d0 + 2];
        v3 = (v3 - bnm[d0 + 3]) * rsqrtf(bnv[d0 + 3] + EPS_BN) * bng[d0 + 3] + bnb[d0 + 3];
        u32 word = enc_fp8x4(v0, v1, v2, v3);
        *(u32*)((unsigned char*)outp + (size_t)cur * DD1 + d0) = word;
    } else {
        #pragma unroll
        for (int k = 0; k < 4; ++k) {
            acc[k] += __shfl_xor(acc[k], 8, 64);
            acc[k] += __shfl_xor(acc[k], 16, 64);
            acc[k] += __shfl_xor(acc[k], 32, 64);
        }
        if (lane < 8) {
            floatx4 pk;
            #pragma unroll
            for (int k = 0; k < 4; ++k) pk[k] = acc[k] * (1.f / NH);
            *(floatx4*)((float*)outp + ((size_t)cur * 7 + f) * OC + lane * 4) = pk;
        }
    }
    acc[0] = acc[1] = acc[2] = acc[3] = 0.f;
}

// ---------------- fused streaming aggregation with ONLINE SOFTMAX (round-5 proven) ----------------
template <int LAYER>
__global__ __launch_bounds__(256) void attn_aggregate(const int* __restrict__ rowptr,
                                                      const int* __restrict__ csr_src,
                                                      const float* __restrict__ as_,
                                                      const float* __restrict__ ad_,
                                                      const unsigned char* __restrict__ h8,
                                                      const float* __restrict__ bias,
                                                      const float* __restrict__ bng,
                                                      const float* __restrict__ bnb,
                                                      const float* __restrict__ bnm,
                                                      const float* __restrict__ bnv,
                                                      void* __restrict__ outp) {
    const int wv = threadIdx.x >> 6, lane = threadIdx.x & 63;
    const int w = blockIdx.x * 4 + wv;
    const int NWAVES = 7 * (NN / GRP);
    if (w >= NWAVES) return;
    const int f  = w % 7;             // feature slice (256 B of the 1792-B row)
    const int g  = w / 7;             // node group
    const int n0 = g * GRP;
    const int off  = f * 256 + lane * 4;
    const int head = f * 8 + (lane >> 3);

    const int e0 = rowptr[n0], e1 = rowptr[n0 + GRP];
    int cur = n0;
    int bound = rowptr[n0 + 1];
    float adv = ad_[(size_t)cur * NH + head];

    float acc[4] = {0.f, 0.f, 0.f, 0.f};
    float m = -1e30f, den = 0.f;

    for (int e = e0; e < e1; e += EB) {
        u32   hv[EB];
        float sv[EB];
        #pragma unroll
        for (int i = 0; i < EB; ++i) {
            int idx = (e + i < e1) ? e + i : e1 - 1;
            int s = csr_src[idx];
            hv[i] = *(const u32*)(h8 + (size_t)s * DD1 + off);
            sv[i] = as_[(size_t)s * NH + head];
        }
        #pragma unroll
        for (int i = 0; i < EB; ++i) {
            if (e + i >= e1) break;
            if (e + i >= bound) {
                flush_node<LAYER>(acc, den, cur, f, lane, bias, bng, bnb, bnm, bnv, outp);
                ++cur;
                bound = rowptr[cur + 1];
                adv = ad_[(size_t)cur * NH + head];
                m = -1e30f; den = 0.f;
            }
            float lr = sv[i] + adv;
            lr = lr > 0.f ? lr : 0.2f * lr;
            float wgt;
            if (lr > m) {
                float scale = __expf(m - lr);
                den = den * scale + 1.f;
                #pragma unroll
                for (int k = 0; k < 4; ++k) acc[k] *= scale;
                m = lr;
                wgt = 1.f;
            } else {
                wgt = __expf(lr - m);
                den += wgt;
            }
            fma_fp8x4(hv[i], wgt, acc);
        }
    }
    flush_node<LAYER>(acc, den, cur, f, lane, bias, bng, bnb, bnm, bnv, outp);
}

// ---------------- mean pool: sorted-batch segmented reduction, minimal atomics ----------------
__global__ __launch_bounds__(256) void pool_kernel(const float* __restrict__ h2part,
                                                   const int* __restrict__ batch,
                                                   float* __restrict__ sums,
                                                   float* __restrict__ cnt) {
    __shared__ float red[4][OC];
    const int g = blockIdx.x >> 3, c = blockIdx.x & 7;
    const int t = threadIdx.x;
    const int ch = t & 31, nl = t >> 5;
    int lo = 0, hi = NN;
    while (lo < hi) { int mid = (lo + hi) >> 1; if (batch[mid] < g) lo = mid + 1; else hi = mid; }
    const int s = lo;
    hi = NN;
    while (lo < hi) { int mid = (lo + hi) >> 1; if (batch[mid] <= g) lo = mid + 1; else hi = mid; }
    const int e = lo;
    const int len = e - s;
    const int n0 = s + (len * c) / 8;
    const int n1 = s + (len * (c + 1)) / 8;
    float acc = 0.f;
    for (int n = n0 + nl; n < n1; n += 8) {
        const float* p = h2part + (size_t)n * 7 * OC + ch;
        float a = 0.f;
        #pragma unroll
        for (int f = 0; f < 7; ++f) a += p[f * OC];
        acc += a;
    }
    acc += __shfl_xor(acc, 32, 64);
    if ((t & 32) == 0) red[t >> 6][ch] = acc;
    __syncthreads();
    if (t < OC) {
        float total = red[0][t] + red[1][t] + red[2][t] + red[3][t];
        atomicAdd(&sums[g * OC + t], total);
    }
    if (t == 0 && c == 0) cnt[g] = (float)len;
}

// final: pooled = sums/cnt; v = BN2(pooled + b2); out = v @ lin_w + lin_b
__global__ __launch_bounds__(128) void final_kernel(const float* __restrict__ sums,
                                                    const float* __restrict__ cnt,
                                                    const float* __restrict__ b2,
                                                    const float* __restrict__ bn2g,
                                                    const float* __restrict__ bn2b,
                                                    const float* __restrict__ bn2m,
                                                    const float* __restrict__ bn2v,
                                                    const float* __restrict__ lin_w,
                                                    const float* __restrict__ lin_b,
                                                    float* __restrict__ out) {
    int t = threadIdx.x;
    if (t >= NG * 2) return;
    int g = t >> 1, c = t & 1;
    float invc = 1.f / fmaxf(cnt[g], 1.f);
    float acc = lin_b[c];
    #pragma unroll
    for (int o = 0; o < OC; ++o) {
        float pooled = sums[g * OC + o] * invc + b2[o];
        float v = (pooled - bn2m[o]) * rsqrtf(bn2v[o] + EPS_BN) * bn2g[o] + bn2b[o];
        acc += v * lin_w[o * 2 + c];
    }
    out[t] = acc;
}

// ---------------- host-side launch ----------------
extern "C" void kernel_launch(void* const* d_in, const int* in_sizes, int n_in,
                              void* d_out, int out_size, void* d_ws, size_t ws_size,
                              hipStream_t stream) {
    const float* x    = (const float*)d_in[0];
    const int*   ei   = (const int*)d_in[1];
    const int*   bat  = (const int*)d_in[2];
    const float* W1   = (const float*)d_in[3];
    const float* at_s1 = (const float*)d_in[4];
    const float* at_d1 = (const float*)d_in[5];
    const float* b1   = (const float*)d_in[6];
    const float* bn1g = (const float*)d_in[7];
    const float* bn1b = (const float*)d_in[8];
    const float* bn1m = (const float*)d_in[9];
    const float* bn1v = (const float*)d_in[10];
    const float* W2   = (const float*)d_in[11];
    const float* at_s2 = (const float*)d_in[12];
    const float* at_d2 = (const float*)d_in[13];
    const float* b2   = (const float*)d_in[14];
    const float* bn2g = (const float*)d_in[15];
    const float* bn2b = (const float*)d_in[16];
    const float* bn2m = (const float*)d_in[17];
    const float* bn2v = (const float*)d_in[18];
    const float* linw = (const float*)d_in[19];
    const float* linb = (const float*)d_in[20];
    float* out = (float*)d_out;

    char* wsp = (char*)d_ws;
    auto alloc = [&](size_t bytes) -> void* {
        void* p = (void*)wsp;
        wsp += (bytes + 255) & ~(size_t)255;
        return p;
    };
    unsigned char*  h8   = (unsigned char*)alloc((size_t)NN * DD1);     // fp8 gemm output
    unsigned char*  h1p  = (unsigned char*)alloc((size_t)NN * DD1);     // agg1 out, FP8 (gemm_fp8 A, layer 2)
    unsigned char*  xb8  = (unsigned char*)alloc((size_t)NN * NF);      // x in fp8 (gemm_fp8 A, layer 1)
    unsigned char*  w1t8 = (unsigned char*)alloc((size_t)DD1 * NF);     // W1^T * 8, fp8
    unsigned char*  w2t8 = (unsigned char*)alloc((size_t)DD1 * DD1);    // W2^T * 16, fp8
    float* asb   = (float*)alloc((size_t)NN * NH * 4);
    float* adb   = (float*)alloc((size_t)NN * NH * 4);
    int*   deg   = (int*)alloc((size_t)NN * 4);
    int*   rowp  = (int*)alloc((size_t)(NN + 1) * 4);
    int*   curs  = (int*)alloc((size_t)NN * 4);
    int*   csr   = (int*)alloc((size_t)ETOT * 4);
    float* h2part = (float*)alloc((size_t)NN * 7 * OC * 4);
    float* sums  = (float*)alloc((size_t)(NG * OC + NG) * 4);
    float* cnt   = sums + NG * OC;

    hipMemsetAsync(deg, 0, (size_t)NN * 4, stream);
    hipMemsetAsync(sums, 0, (size_t)(NG * OC + NG) * 4, stream);

    cast_fp8_kernel<<<(NN * NF + 255) / 256, 256, 0, stream>>>(x, xb8, NN * NF);
    transpose_fp8_kernel<<<dim3(DD1 / 32, NF / 32), 256, 0, stream>>>(W1, w1t8, NF, DD1, W1SCL);
    transpose_fp8_kernel<<<dim3(DD1 / 32, DD1 / 32), 256, 0, stream>>>(W2, w2t8, DD1, DD1, W2SCL);
    hist_kernel<<<(ETOT + 255) / 256, 256, 0, stream>>>(ei, deg);
    scan_kernel<<<1, 1024, 0, stream>>>(deg, rowp, curs);
    scatter_kernel<<<(ETOT + 255) / 256, 256, 0, stream>>>(ei, curs, csr);

    const int AGG_BLOCKS = (7 * (NN / GRP) + 3) / 4;
    const int NBY192 = (NN + 191) / 192;                   // 105
    const int GEMM_BLOCKS = NBY192 * (DD1 / 256);          // 735

    // layer 1 (fp8 gemm, K=128 single K-tile, fused scores)
    gemm_fp8<<<GEMM_BLOCKS, 512, 0, stream>>>(xb8, w1t8, h8, at_s1, at_d1, asb, adb, NN, DD1, NF, 1.0f / W1SCL);
    attn_aggregate<1><<<AGG_BLOCKS, 256, 0, stream>>>(rowp, csr, asb, adb, h8, b1, bn1g, bn1b, bn1m, bn1v, (void*)h1p);

    // layer 2 (fp8 gemm, fused scores)
    gemm_fp8<<<GEMM_BLOCKS, 512, 0, stream>>>(h1p, w2t8, h8, at_s2, at_d2, asb, adb, NN, DD1, DD1, 1.0f / W2SCL);
    attn_aggregate<2><<<AGG_BLOCKS, 256, 0, stream>>>(rowp, csr, asb, adb, h8, b2, bn2g, bn2b, bn2m, bn2v, (void*)h2part);

    pool_kernel<<<NG * 8, 256, 0, stream>>>(h2part, bat, sums, cnt);
    final_kernel<<<1, 128, 0, stream>>>(sums, cnt, b2, bn2g, bn2b, bn2m, bn2v, linw, linb, out);
}